// Round 4
// baseline (275.121 us; speedup 1.0000x reference)
//
#include <hip/hip_runtime.h>
#include <math.h>

#define NB 64
#define NA 5
#define NC 80
#define NH 38
#define NW 38
#define MAXB 50
#define PLANE (NH*NW)          // 1444
#define PER_B (NA*PLANE)       // 7220
#define NCH (5+NC)             // 85
#define MAIN_BX ((PER_B + 255) / 256)   // 29
#define NPART (MAIN_BX * NB)            // 1856

typedef unsigned long long ull;

__constant__ float c_aw[5] = {1.3221f, 3.19275f, 5.05587f, 9.47112f, 11.2364f};
__constant__ float c_ah[5] = {1.73145f, 4.00944f, 8.09892f, 4.84053f, 10.0071f};

struct Entry {
    int   fidx;    // global flat index into N, or -1 if not a winner
    int   tcls;
    float cm, tc0, tc1, tc2, tc3, tconf;
};

__device__ inline float sigmoidf(float x) { return 1.f / (1.f + expf(-x)); }

// publish partial as (bits, ~bits) — 0xAA poison can never satisfy hi==~lo
__device__ inline void publish(ull* slot, float v) {
    union { float f; unsigned u; } c; c.f = v;
    ull packed = ((ull)(~c.u) << 32) | (ull)c.u;
    __hip_atomic_store(slot, packed, __ATOMIC_RELEASE, __HIP_MEMORY_SCOPE_AGENT);
}

// ---- Single fused kernel: prep (wave0/LDS) + loss + grid-wide reduction ----
__global__ __launch_bounds__(256)
void main_kernel(const float* __restrict__ out, const float* __restrict__ target,
                 ull* __restrict__ slots, float* __restrict__ loss) {
    const int b   = blockIdx.y;
    const int bx  = blockIdx.x;
    const int tid = threadIdx.x;

    __shared__ float4 sbox[MAXB];   // gt corners: x1,y1,x2,y2
    __shared__ float  sarea[MAXB];  // gt area
    __shared__ Entry  sent[MAXB];
    __shared__ int    sfx[64];
    __shared__ int    snv;
    __shared__ int    sobj_cnt;
    __shared__ int    sobj_idx[MAXB];

    if (tid == 0) sobj_cnt = 0;

    // ---------------- wave-0 prep (redundant per block, all in LDS) --------
    if (tid < 64) {
        const float* tb = target + b * MAXB * 5;
        int t = tid;
        bool has = (t < MAXB);
        float cls = 0.f, x = 0.f, y = 0.f, w = 0.f, h = 0.f;
        if (has) {
            cls = tb[t * 5 + 0];
            x   = tb[t * 5 + 1];
            y   = tb[t * 5 + 2];
            w   = tb[t * 5 + 3];
            h   = tb[t * 5 + 4];
        }
        unsigned long long mask = __ballot(has && (x > 0.f));
        bool valid = has && (((~mask) & ((1ull << (t + 1)) - 1ull)) == 0ull);

        float gx = x * NW, gy = y * NH, gw = w * NW, gh = h * NH;

        int best = 0; float bestr = -1.f;
        #pragma unroll
        for (int a = 0; a < NA; a++) {
            float inter = fminf(c_aw[a], gw) * fminf(c_ah[a], gh);
            float uni   = c_aw[a] * c_ah[a] + gw * gh - inter;
            float r = inter / fmaxf(uni, 1e-10f);
            if (r > bestr) { bestr = r; best = a; }
        }
        int gi = min(max((int)gx, 0), NW - 1);
        int gj = min(max((int)gy, 0), NH - 1);
        int fidx = b * PER_B + best * PLANE + gj * NW + gi;

        float iou_sel = 0.f;
        if (valid) {
            int base = ((b * NA + best) * NCH) * PLANE + gj * NW + gi;
            float o0 = out[base];
            float o1 = out[base + PLANE];
            float o2 = out[base + 2 * PLANE];
            float o3 = out[base + 3 * PLANE];
            float px = sigmoidf(o0) + (float)gi;
            float py = sigmoidf(o1) + (float)gj;
            float pw = expf(o2) * c_aw[best];
            float ph = expf(o3) * c_ah[best];
            float iw = fmaxf(fminf(gx + gw*0.5f, px + pw*0.5f) - fmaxf(gx - gw*0.5f, px - pw*0.5f), 0.f);
            float ih = fmaxf(fminf(gy + gh*0.5f, py + ph*0.5f) - fmaxf(gy - gh*0.5f, py - ph*0.5f), 0.f);
            float inter = iw * ih;
            float uni = gw * gh + pw * ph - inter;
            iou_sel = inter / fmaxf(uni, 1e-10f);
        }

        // winner = last valid box with this fidx (wave-lockstep LDS)
        sfx[t] = valid ? fidx : -1;
        bool winner = valid;
        if (valid) {
            for (int s = t + 1; s < MAXB; s++)
                if (sfx[s] == fidx) { winner = false; break; }
        }

        if (has) {
            sbox[t]  = make_float4(gx - gw*0.5f, gy - gh*0.5f, gx + gw*0.5f, gy + gh*0.5f);
            sarea[t] = gw * gh;
            Entry e;
            e.fidx  = winner ? fidx : -1;
            e.tcls  = (int)cls;
            e.cm    = 2.f - w * h;
            e.tc0   = gx - (float)gi;
            e.tc1   = gy - (float)gj;
            e.tc2   = logf(gw / c_aw[best]);
            e.tc3   = logf(gh / c_ah[best]);
            e.tconf = iou_sel;
            sent[t] = e;
        }
        if (t == 0) {
            unsigned long long nm = ~mask;
            snv = min(__ffsll((unsigned long long)nm) - 1, MAXB);
        }
    }
    __syncthreads();

    // ---------------- block-local obj (winner) list -------------------------
    const int nlo = b * PER_B + bx * 256;   // block covers n in [nlo, nlo+256)
    if (tid < MAXB) {
        int f = sent[tid].fidx;
        if (f >= nlo && f < nlo + 256) {
            int slot = atomicAdd(&sobj_cnt, 1);
            sobj_idx[slot] = tid;
        }
    }
    __syncthreads();

    // ---------------- per-cell loss -----------------------------------------
    int m = bx * 256 + tid;
    float part = 0.f;
    if (m < PER_B) {
        int a   = m / PLANE;
        int pos = m - a * PLANE;
        int j   = pos / NW;
        int i   = pos - j * NW;

        int base = ((b * NA + a) * NCH) * PLANE + pos;
        float o0 = out[base];
        float o1 = out[base + PLANE];
        float o2 = out[base + 2 * PLANE];
        float o3 = out[base + 3 * PLANE];
        float o4 = out[base + 4 * PLANE];

        float s0   = sigmoidf(o0);
        float s1   = sigmoidf(o1);
        float conf = sigmoidf(o4);
        float pw = expf(o2) * c_aw[a];
        float ph = expf(o3) * c_ah[a];
        float px1 = s0 + (float)i - pw * 0.5f;
        float px2 = px1 + pw;
        float py1 = s1 + (float)j - ph * 0.5f;
        float py2 = py1 + ph;
        float area_p = pw * ph;

        // any GT box with IoU > 0.6?  (division-free)
        bool gt06 = false;
        int nv = snv;
        for (int s = 0; s < nv; s++) {
            float4 g = sbox[s];
            float iw = fmaxf(fminf(px2, g.z) - fmaxf(px1, g.x), 0.f);
            float ih = fmaxf(fminf(py2, g.w) - fmaxf(py1, g.y), 0.f);
            float inter = iw * ih;
            float uni = area_p + sarea[s] - inter;
            gt06 = gt06 || (inter > 0.6f * fmaxf(uni, 1e-10f));
        }

        // defaults (SEEN=0 < 12800)
        float cm = 0.01f, tc0 = 0.5f, tc1 = 0.5f, tc2 = 0.f, tc3 = 0.f, tconf = 0.f;
        bool is_obj = false;
        int tcls = 0;
        int n = nlo + tid;
        int oc = sobj_cnt;
        for (int s = 0; s < oc; s++) {
            int e = sobj_idx[s];
            if (sent[e].fidx == n) {
                is_obj = true;
                cm  = sent[e].cm;
                tc0 = sent[e].tc0;  tc1 = sent[e].tc1;
                tc2 = sent[e].tc2;  tc3 = sent[e].tc3;
                tconf = sent[e].tconf;
                tcls  = sent[e].tcls;
            }
        }
        float conf_mask = is_obj ? 5.f : (gt06 ? 0.f : 1.f);

        float d;
        d = (s0   - tc0)   * cm;        part += d * d;
        d = (s1   - tc1)   * cm;        part += d * d;
        d = (o2   - tc2)   * cm;        part += d * d;
        d = (o3   - tc3)   * cm;        part += d * d;
        d = (conf - tconf) * conf_mask; part += d * d;

        // fused class cross-entropy at obj cells (~1-3 threads per block)
        if (is_obj) {
            const float* cp = out + base + 5 * PLANE;
            float mx = -INFINITY, s = 0.f, tv = 0.f;
            for (int c = 0; c < NC; c++) {
                float v = cp[c * PLANE];
                if (c == tcls) tv = v;
                float mn = fmaxf(mx, v);
                s = s * expf(mx - mn) + expf(v - mn);
                mx = mn;
            }
            part += mx + logf(s) - tv;   // lse - logit[tcls]
        }
    }

    // block reduction (4 waves of 64)
    for (int off = 32; off > 0; off >>= 1) part += __shfl_down(part, off);
    __shared__ float wsum[4];
    int wid = tid >> 6, lane = tid & 63;
    if (lane == 0) wsum[wid] = part;
    __syncthreads();
    if (tid == 0)
        publish(&slots[b * MAIN_BX + bx], wsum[0] + wsum[1] + wsum[2] + wsum[3]);

    // ---------------- block (0,0): spin-collect all partials, write loss ----
    if (bx == 0 && b == 0) {
        __syncthreads();               // wsum reuse below
        float s = 0.f;
        for (int i = tid; i < NPART; i += 256) {
            ull p;
            for (;;) {
                p = __hip_atomic_load(&slots[i], __ATOMIC_ACQUIRE, __HIP_MEMORY_SCOPE_AGENT);
                unsigned lo = (unsigned)p, hi = (unsigned)(p >> 32);
                if (hi == ~lo) break;
                __builtin_amdgcn_s_sleep(1);
            }
            union { unsigned u; float f; } c; c.u = (unsigned)p;
            s += c.f;
        }
        for (int off = 32; off > 0; off >>= 1) s += __shfl_down(s, off);
        if (lane == 0) wsum[wid] = s;
        __syncthreads();
        if (tid == 0)
            loss[0] = (wsum[0] + wsum[1] + wsum[2] + wsum[3]) * (1.0f / NB);
    }
}

extern "C" void kernel_launch(void* const* d_in, const int* in_sizes, int n_in,
                              void* d_out, int out_size, void* d_ws, size_t ws_size,
                              hipStream_t stream) {
    const float* out    = (const float*)d_in[0];
    const float* target = (const float*)d_in[1];
    float* loss = (float*)d_out;
    ull*   slots = (ull*)d_ws;     // NPART packed (bits, ~bits) pairs

    dim3 grid(MAIN_BX, NB);
    main_kernel<<<grid, 256, 0, stream>>>(out, target, slots, loss);
}

// Round 5
// 209.662 us; speedup vs baseline: 1.3122x; 1.3122x over previous
//
#include <hip/hip_runtime.h>
#include <math.h>

#define NB 64
#define NA 5
#define NC 80
#define NH 38
#define NW 38
#define MAXB 50
#define PLANE (NH*NW)          // 1444
#define PER_B (NA*PLANE)       // 7220
#define NCH (5+NC)             // 85
#define MAIN_BX ((PER_B + 255) / 256)   // 29
#define NPART (MAIN_BX * NB)            // 1856

__constant__ float c_aw[5] = {1.3221f, 3.19275f, 5.05587f, 9.47112f, 11.2364f};
__constant__ float c_ah[5] = {1.73145f, 4.00944f, 8.09892f, 4.84053f, 10.0071f};

struct Entry {
    int   fidx;    // global flat index into N, or -1 if not a winner
    int   tcls;
    float cm, tc0, tc1, tc2, tc3, tconf;
};

__device__ inline float sigmoidf(float x) { return 1.f / (1.f + expf(-x)); }

// ---- Fused kernel: wave-0 GT prep (LDS) + coord/conf loss + wave-CE --------
__global__ __launch_bounds__(256)
void main_kernel(const float* __restrict__ out, const float* __restrict__ target,
                 float* __restrict__ partial) {
    const int b   = blockIdx.y;
    const int bx  = blockIdx.x;
    const int tid = threadIdx.x;

    __shared__ float4 sbox[MAXB];   // gt corners: x1,y1,x2,y2
    __shared__ float  sarea[MAXB];  // gt area
    __shared__ Entry  sent[MAXB];
    __shared__ int    sfx[64];
    __shared__ int    snv;
    __shared__ int    sobj_cnt;
    __shared__ int    sobj_idx[MAXB];

    if (tid == 0) sobj_cnt = 0;

    // ---------------- wave-0 prep (redundant per block, all in LDS) --------
    if (tid < 64) {
        const float* tb = target + b * MAXB * 5;
        int t = tid;
        bool has = (t < MAXB);
        float cls = 0.f, x = 0.f, y = 0.f, w = 0.f, h = 0.f;
        if (has) {
            cls = tb[t * 5 + 0];
            x   = tb[t * 5 + 1];
            y   = tb[t * 5 + 2];
            w   = tb[t * 5 + 3];
            h   = tb[t * 5 + 4];
        }
        unsigned long long mask = __ballot(has && (x > 0.f));
        bool valid = has && (((~mask) & ((1ull << (t + 1)) - 1ull)) == 0ull);

        float gx = x * NW, gy = y * NH, gw = w * NW, gh = h * NH;

        int best = 0; float bestr = -1.f;
        #pragma unroll
        for (int a = 0; a < NA; a++) {
            float inter = fminf(c_aw[a], gw) * fminf(c_ah[a], gh);
            float uni   = c_aw[a] * c_ah[a] + gw * gh - inter;
            float r = inter / fmaxf(uni, 1e-10f);
            if (r > bestr) { bestr = r; best = a; }
        }
        int gi = min(max((int)gx, 0), NW - 1);
        int gj = min(max((int)gy, 0), NH - 1);
        int fidx = b * PER_B + best * PLANE + gj * NW + gi;

        float iou_sel = 0.f;
        if (valid) {
            int base = ((b * NA + best) * NCH) * PLANE + gj * NW + gi;
            float o0 = out[base];
            float o1 = out[base + PLANE];
            float o2 = out[base + 2 * PLANE];
            float o3 = out[base + 3 * PLANE];
            float px = sigmoidf(o0) + (float)gi;
            float py = sigmoidf(o1) + (float)gj;
            float pw = expf(o2) * c_aw[best];
            float ph = expf(o3) * c_ah[best];
            float iw = fmaxf(fminf(gx + gw*0.5f, px + pw*0.5f) - fmaxf(gx - gw*0.5f, px - pw*0.5f), 0.f);
            float ih = fmaxf(fminf(gy + gh*0.5f, py + ph*0.5f) - fmaxf(gy - gh*0.5f, py - ph*0.5f), 0.f);
            float inter = iw * ih;
            float uni = gw * gh + pw * ph - inter;
            iou_sel = inter / fmaxf(uni, 1e-10f);
        }

        // winner = last valid box with this fidx (wave-lockstep LDS)
        sfx[t] = valid ? fidx : -1;
        bool winner = valid;
        if (valid) {
            for (int s = t + 1; s < MAXB; s++)
                if (sfx[s] == fidx) { winner = false; break; }
        }

        if (has) {
            sbox[t]  = make_float4(gx - gw*0.5f, gy - gh*0.5f, gx + gw*0.5f, gy + gh*0.5f);
            sarea[t] = gw * gh;
            Entry e;
            e.fidx  = winner ? fidx : -1;
            e.tcls  = (int)cls;
            e.cm    = 2.f - w * h;
            e.tc0   = gx - (float)gi;
            e.tc1   = gy - (float)gj;
            e.tc2   = logf(gw / c_aw[best]);
            e.tc3   = logf(gh / c_ah[best]);
            e.tconf = iou_sel;
            sent[t] = e;
        }
        if (t == 0) {
            unsigned long long nm = ~mask;
            snv = min(__ffsll((unsigned long long)nm) - 1, MAXB);
        }
    }
    __syncthreads();

    // ---------------- block-local obj (winner) list -------------------------
    const int nlo = b * PER_B + bx * 256;   // block covers n in [nlo, nlo+256)
    if (tid < MAXB) {
        int f = sent[tid].fidx;
        if (f >= nlo && f < nlo + 256) {
            int slot = atomicAdd(&sobj_cnt, 1);
            sobj_idx[slot] = tid;
        }
    }
    __syncthreads();

    // ---------------- per-cell coord + conf loss ----------------------------
    int m = bx * 256 + tid;
    float part = 0.f;
    if (m < PER_B) {
        int a   = m / PLANE;
        int pos = m - a * PLANE;
        int j   = pos / NW;
        int i   = pos - j * NW;

        int base = ((b * NA + a) * NCH) * PLANE + pos;
        float o0 = out[base];
        float o1 = out[base + PLANE];
        float o2 = out[base + 2 * PLANE];
        float o3 = out[base + 3 * PLANE];
        float o4 = out[base + 4 * PLANE];

        float s0   = sigmoidf(o0);
        float s1   = sigmoidf(o1);
        float conf = sigmoidf(o4);
        float pw = expf(o2) * c_aw[a];
        float ph = expf(o3) * c_ah[a];
        float px1 = s0 + (float)i - pw * 0.5f;
        float px2 = px1 + pw;
        float py1 = s1 + (float)j - ph * 0.5f;
        float py2 = py1 + ph;
        float area_p = pw * ph;

        // any GT box with IoU > 0.6?  (division-free)
        bool gt06 = false;
        int nv = snv;
        for (int s = 0; s < nv; s++) {
            float4 g = sbox[s];
            float iw = fmaxf(fminf(px2, g.z) - fmaxf(px1, g.x), 0.f);
            float ih = fmaxf(fminf(py2, g.w) - fmaxf(py1, g.y), 0.f);
            float inter = iw * ih;
            float uni = area_p + sarea[s] - inter;
            gt06 = gt06 || (inter > 0.6f * fmaxf(uni, 1e-10f));
        }

        // defaults (SEEN=0 < 12800)
        float cm = 0.01f, tc0 = 0.5f, tc1 = 0.5f, tc2 = 0.f, tc3 = 0.f, tconf = 0.f;
        bool is_obj = false;
        int n = nlo + tid;
        int oc = sobj_cnt;
        for (int s = 0; s < oc; s++) {
            int e = sobj_idx[s];
            if (sent[e].fidx == n) {
                is_obj = true;
                cm  = sent[e].cm;
                tc0 = sent[e].tc0;  tc1 = sent[e].tc1;
                tc2 = sent[e].tc2;  tc3 = sent[e].tc3;
                tconf = sent[e].tconf;
            }
        }
        float conf_mask = is_obj ? 5.f : (gt06 ? 0.f : 1.f);

        float d;
        d = (s0   - tc0)   * cm;        part += d * d;
        d = (s1   - tc1)   * cm;        part += d * d;
        d = (o2   - tc2)   * cm;        part += d * d;
        d = (o3   - tc3)   * cm;        part += d * d;
        d = (conf - tconf) * conf_mask; part += d * d;
    }

    // ---------------- wave-parallel class CE over this block's obj list -----
    // Each wave takes entries round-robin; 64 lanes fetch the 80 strided
    // logits in 2 vector issues (one latency shot vs 80 serial loads).
    {
        int wid  = tid >> 6, lane = tid & 63;
        int oc   = sobj_cnt;
        for (int e = wid; e < oc; e += 4) {
            Entry ent = sent[sobj_idx[e]];
            int rel  = ent.fidx - b * PER_B;
            int a    = rel / PLANE;
            int pos  = rel - a * PLANE;
            const float* cp = out + ((b * NA + a) * NCH + 5) * PLANE + pos;

            float v1 = cp[lane * PLANE];                                   // 0..63
            float v2 = (lane < NC - 64) ? cp[(64 + lane) * PLANE] : -INFINITY; // 64..79

            float mx = fmaxf(v1, v2);
            for (int off = 32; off > 0; off >>= 1) mx = fmaxf(mx, __shfl_xor(mx, off));
            float s = expf(v1 - mx) + ((lane < NC - 64) ? expf(v2 - mx) : 0.f);
            for (int off = 32; off > 0; off >>= 1) s += __shfl_xor(s, off);

            int tc = ent.tcls;
            float tv = (tc < 64) ? __shfl(v1, tc) : __shfl(v2, tc - 64);
            if (lane == 0) part += mx + logf(s) - tv;   // lse - logit[tcls]
        }
    }

    // ---------------- block reduction (4 waves of 64) -----------------------
    for (int off = 32; off > 0; off >>= 1) part += __shfl_down(part, off);
    __shared__ float wsum[4];
    int wid = tid >> 6, lane = tid & 63;
    if (lane == 0) wsum[wid] = part;
    __syncthreads();
    if (tid == 0)
        partial[b * MAIN_BX + bx] = wsum[0] + wsum[1] + wsum[2] + wsum[3];
}

// ---------------- final reduction (1 block), writes d_out -------------------
__global__ __launch_bounds__(256)
void final_kernel(const float* __restrict__ partial, float* __restrict__ loss) {
    int tid = threadIdx.x;
    float s = 0.f;
    for (int i = tid; i < NPART; i += 256) s += partial[i];
    for (int off = 32; off > 0; off >>= 1) s += __shfl_down(s, off);
    __shared__ float wsum[4];
    int wid = tid >> 6, lane = tid & 63;
    if (lane == 0) wsum[wid] = s;
    __syncthreads();
    if (tid == 0)
        loss[0] = (wsum[0] + wsum[1] + wsum[2] + wsum[3]) * (1.0f / NB);
}

extern "C" void kernel_launch(void* const* d_in, const int* in_sizes, int n_in,
                              void* d_out, int out_size, void* d_ws, size_t ws_size,
                              hipStream_t stream) {
    const float* out    = (const float*)d_in[0];
    const float* target = (const float*)d_in[1];
    float* loss    = (float*)d_out;
    float* partial = (float*)d_ws;     // NPART floats

    dim3 grid(MAIN_BX, NB);
    main_kernel<<<grid, 256, 0, stream>>>(out, target, partial);
    final_kernel<<<1, 256, 0, stream>>>(partial, loss);
}